// Round 1
// baseline (2350.879 us; speedup 1.0000x reference)
//
#include <hip/hip_runtime.h>

// Problem constants (PathDecoder): B=256, L=192, H=320, E=128, V=27000, T=8
constexpr int Bn = 256;
constexpr int Ln = 192;
constexpr int Hn = 320;
constexpr int En = 128;
constexpr int Vn = 27000;
constexpr int Tn = 8;
constexpr float NEGV   = -1e9f;
constexpr float LN_EPS = 1e-5f;

__device__ __forceinline__ float sigmoidf_(float x) { return 1.f / (1.f + expf(-x)); }

// ---------------------------------------------------------------------------
// K0: h0 = c0 = mean of context over valid length (pads are zero); tok = SOS=1
// grid: (B), block: (H=320)
__global__ __launch_bounds__(320) void k_init(const float* __restrict__ ctx,
                                              const int* __restrict__ lens,
                                              float* __restrict__ h,
                                              float* __restrict__ c,
                                              int* __restrict__ tok) {
  int b = blockIdx.x, t = threadIdx.x;
  const float* p = ctx + (size_t)b * Ln * Hn + t;
  float s = 0.f;
  for (int l = 0; l < Ln; ++l) s += p[(size_t)l * Hn];
  float hv = s / (float)lens[b];
  h[b * Hn + t] = hv;
  c[b * Hn + t] = hv;
  if (t == 0) tok[b] = 1;
}

// ---------------------------------------------------------------------------
// K1: gates = emb[tok] @ w_ih^T + h @ w_hh^T + b_ih + b_hh, then LSTM cell.
// Tiled GEMM over x=[emb|h] (K=448). Block tile: 64 b-rows x (4 gates x 16 h-cols).
// grid: (H/16=20, B/64=4), block: 256 (16x16), each thread: 4 b x 4 gates for one h-col.
__global__ __launch_bounds__(256) void k_gates_lstm(
    const float* __restrict__ emb, const int* __restrict__ tok,
    const float* __restrict__ w_ih, const float* __restrict__ w_hh,
    const float* __restrict__ b_ih, const float* __restrict__ b_hh,
    const float* __restrict__ h_in, const float* __restrict__ c_in,
    float* __restrict__ h_out, float* __restrict__ c_out) {
  __shared__ float Xs[64][36];
  __shared__ float Ws[32][68];
  __shared__ float bias[64];
  __shared__ int   toks[64];

  int tid = threadIdx.x;
  int tx = tid & 15, ty = tid >> 4;
  int j0 = blockIdx.x * 16;  // h-column base
  int b0 = blockIdx.y * 64;

  if (tid < 64) {
    toks[tid] = tok[b0 + tid];
    int g = tid >> 4;
    int r = g * Hn + j0 + (tid & 15);
    bias[tid] = b_ih[r] + b_hh[r];
  }
  __syncthreads();

  float acc[4][4];
#pragma unroll
  for (int i = 0; i < 4; ++i)
#pragma unroll
    for (int j = 0; j < 4; ++j) acc[i][j] = 0.f;

  for (int k0 = 0; k0 < En + Hn; k0 += 32) {
    // X tile: 64 b x 32 k  (512 float4 slots, 2 per thread)
#pragma unroll
    for (int jj = 0; jj < 2; ++jj) {
      int s = tid + jj * 256;
      int bl = s >> 3, k4 = s & 7;
      int k = k0 + k4 * 4;
      float4 v;
      if (k < En)
        v = *(const float4*)(emb + (size_t)toks[bl] * En + k);
      else
        v = *(const float4*)(h_in + (size_t)(b0 + bl) * Hn + (k - En));
      *(float4*)&Xs[bl][k4 * 4] = v;
    }
    // W tile: 64 rows (gate*16 + hcol) x 32 k, transposed store
#pragma unroll
    for (int jj = 0; jj < 2; ++jj) {
      int s = tid + jj * 256;
      int rw = s >> 3, k4 = s & 7;
      int k = k0 + k4 * 4;
      int g = rw >> 4;
      int r = g * Hn + j0 + (rw & 15);
      float4 v;
      if (k < En)
        v = *(const float4*)(w_ih + (size_t)r * En + k);
      else
        v = *(const float4*)(w_hh + (size_t)r * Hn + (k - En));
      Ws[k4 * 4 + 0][rw] = v.x;
      Ws[k4 * 4 + 1][rw] = v.y;
      Ws[k4 * 4 + 2][rw] = v.z;
      Ws[k4 * 4 + 3][rw] = v.w;
    }
    __syncthreads();
#pragma unroll 4
    for (int k = 0; k < 32; ++k) {
      float a0 = Xs[ty * 4 + 0][k], a1 = Xs[ty * 4 + 1][k];
      float a2 = Xs[ty * 4 + 2][k], a3 = Xs[ty * 4 + 3][k];
      float w0 = Ws[k][tx], w1 = Ws[k][tx + 16], w2 = Ws[k][tx + 32], w3 = Ws[k][tx + 48];
      acc[0][0] += a0 * w0; acc[0][1] += a0 * w1; acc[0][2] += a0 * w2; acc[0][3] += a0 * w3;
      acc[1][0] += a1 * w0; acc[1][1] += a1 * w1; acc[1][2] += a1 * w2; acc[1][3] += a1 * w3;
      acc[2][0] += a2 * w0; acc[2][1] += a2 * w1; acc[2][2] += a2 * w2; acc[2][3] += a2 * w3;
      acc[3][0] += a3 * w0; acc[3][1] += a3 * w1; acc[3][2] += a3 * w2; acc[3][3] += a3 * w3;
    }
    __syncthreads();
  }

#pragma unroll
  for (int mi = 0; mi < 4; ++mi) {
    int b = b0 + ty * 4 + mi;
    int hc = j0 + tx;
    float iv = acc[mi][0] + bias[tx];
    float fv = acc[mi][1] + bias[16 + tx];
    float gv = acc[mi][2] + bias[32 + tx];
    float ov = acc[mi][3] + bias[48 + tx];
    float co = c_in[(size_t)b * Hn + hc];
    float cn = sigmoidf_(fv) * co + sigmoidf_(iv) * tanhf(gv);
    float hn = sigmoidf_(ov) * tanhf(cn);
    c_out[(size_t)b * Hn + hc] = cn;
    h_out[(size_t)b * Hn + hc] = hn;
  }
}

// ---------------------------------------------------------------------------
// K2: attention for one b per block: ah = attn_w @ h; scores; masked softmax;
// ctx = sum_l attn[l] * context[b,l,:]
// grid: (B), block: 256
__global__ __launch_bounds__(256) void k_attn(
    const float* __restrict__ enc, const int* __restrict__ lens,
    const float* __restrict__ attn_w, const float* __restrict__ h_new,
    float* __restrict__ ctx_out) {
  __shared__ float hs[Hn];
  __shared__ float ahs[Hn];
  __shared__ float ss[Ln];
  __shared__ float red0, red1;

  int b = blockIdx.x, tid = threadIdx.x;
  for (int i = tid; i < Hn; i += 256) hs[i] = h_new[(size_t)b * Hn + i];
  __syncthreads();

  // ah[i] = sum_k attn_w[i,k] * h[k]
  for (int i = tid; i < Hn; i += 256) {
    const float* w = attn_w + (size_t)i * Hn;
    float s = 0.f;
#pragma unroll 4
    for (int k = 0; k < Hn; ++k) s += w[k] * hs[k];
    ahs[i] = s;
  }
  __syncthreads();

  // scores: one wave per row group
  int lane = tid & 63, wv = tid >> 6;
  int len = lens[b];
  for (int l = wv; l < Ln; l += 4) {
    const float* cp = enc + ((size_t)b * Ln + l) * Hn;
    float s = 0.f;
#pragma unroll
    for (int c5 = 0; c5 < 5; ++c5) s += cp[lane + 64 * c5] * ahs[lane + 64 * c5];
#pragma unroll
    for (int off = 32; off > 0; off >>= 1) s += __shfl_xor(s, off, 64);
    if (lane == 0) ss[l] = s + ((l < len) ? 0.f : NEGV);
  }
  __syncthreads();

  // softmax over L=192
  if (tid < 64) {
    float m = -3.402823466e38f;
    for (int l = tid; l < Ln; l += 64) m = fmaxf(m, ss[l]);
#pragma unroll
    for (int off = 32; off > 0; off >>= 1) m = fmaxf(m, __shfl_xor(m, off, 64));
    if (tid == 0) red0 = m;
  }
  __syncthreads();
  float m = red0;
  for (int l = tid; l < Ln; l += 256) ss[l] = expf(ss[l] - m);
  __syncthreads();
  if (tid < 64) {
    float s = 0.f;
    for (int l = tid; l < Ln; l += 64) s += ss[l];
#pragma unroll
    for (int off = 32; off > 0; off >>= 1) s += __shfl_xor(s, off, 64);
    if (tid == 0) red1 = s;
  }
  __syncthreads();
  float inv = 1.f / red1;
  for (int l = tid; l < Ln; l += 256) ss[l] *= inv;
  __syncthreads();

  // ctx[h] = sum_l p[l] * enc[b,l,h]
  for (int h = tid; h < Hn; h += 256) {
    const float* cp = enc + (size_t)b * Ln * Hn + h;
    float a = 0.f;
#pragma unroll 4
    for (int l = 0; l < Ln; ++l) a += ss[l] * cp[(size_t)l * Hn];
    ctx_out[(size_t)b * Hn + h] = a;
  }
}

// ---------------------------------------------------------------------------
// K3: cat = [h,ctx] @ concat_w^T ; LayerNorm ; tanh -> tcat
// grid: (B), block: 256
__global__ __launch_bounds__(256) void k_concat_ln(
    const float* __restrict__ h_new, const float* __restrict__ ctxv,
    const float* __restrict__ cw, const float* __restrict__ gamma,
    const float* __restrict__ beta, float* __restrict__ tcat) {
  __shared__ float xs[2 * Hn];
  __shared__ float cs[Hn];
  __shared__ float mu_s, var_s;

  int b = blockIdx.x, tid = threadIdx.x;
  for (int i = tid; i < Hn; i += 256) {
    xs[i] = h_new[(size_t)b * Hn + i];
    xs[Hn + i] = ctxv[(size_t)b * Hn + i];
  }
  __syncthreads();

  for (int i = tid; i < Hn; i += 256) {
    const float* w = cw + (size_t)i * (2 * Hn);
    float s = 0.f;
#pragma unroll 4
    for (int k = 0; k < 2 * Hn; ++k) s += w[k] * xs[k];
    cs[i] = s;
  }
  __syncthreads();

  if (tid < 64) {
    float s = 0.f;
    for (int i = tid; i < Hn; i += 64) s += cs[i];
#pragma unroll
    for (int off = 32; off > 0; off >>= 1) s += __shfl_xor(s, off, 64);
    if (tid == 0) mu_s = s / (float)Hn;
  }
  __syncthreads();
  float mu = mu_s;
  if (tid < 64) {
    float s = 0.f;
    for (int i = tid; i < Hn; i += 64) { float d = cs[i] - mu; s += d * d; }
#pragma unroll
    for (int off = 32; off > 0; off >>= 1) s += __shfl_xor(s, off, 64);
    if (tid == 0) var_s = s / (float)Hn;
  }
  __syncthreads();
  float rstd = 1.f / sqrtf(var_s + LN_EPS);
  for (int i = tid; i < Hn; i += 256) {
    float y = (cs[i] - mu) * rstd * gamma[i] + beta[i];
    tcat[(size_t)b * Hn + i] = tanhf(y);
  }
}

// ---------------------------------------------------------------------------
// K4: out[b,v] = tcat[b,:] . proj_w[v,:]   (M=256, N=27000, K=320) fp32 GEMM
// grid: (ceil(V/128)=211, B/64=4), block 256 (16x16), thread tile 4b x 8v, BK=32
__global__ __launch_bounds__(256) void k_proj(
    const float* __restrict__ tcat, const float* __restrict__ pw,
    float* __restrict__ out) {
  __shared__ float As[64][36];
  __shared__ float Bs[32][132];

  int tid = threadIdx.x;
  int tx = tid & 15, ty = tid >> 4;
  int v0 = blockIdx.x * 128;
  int b0 = blockIdx.y * 64;

  float acc[4][8];
#pragma unroll
  for (int i = 0; i < 4; ++i)
#pragma unroll
    for (int j = 0; j < 8; ++j) acc[i][j] = 0.f;

  for (int k0 = 0; k0 < Hn; k0 += 32) {
#pragma unroll
    for (int jj = 0; jj < 2; ++jj) {
      int s = tid + jj * 256;
      int bl = s >> 3, k4 = s & 7;
      float4 v = *(const float4*)(tcat + (size_t)(b0 + bl) * Hn + k0 + k4 * 4);
      *(float4*)&As[bl][k4 * 4] = v;
    }
#pragma unroll
    for (int jj = 0; jj < 4; ++jj) {
      int s = tid + jj * 256;
      int vl = s >> 3, k4 = s & 7;
      int v = v0 + vl;
      float4 w = make_float4(0.f, 0.f, 0.f, 0.f);
      if (v < Vn) w = *(const float4*)(pw + (size_t)v * Hn + k0 + k4 * 4);
      Bs[k4 * 4 + 0][vl] = w.x;
      Bs[k4 * 4 + 1][vl] = w.y;
      Bs[k4 * 4 + 2][vl] = w.z;
      Bs[k4 * 4 + 3][vl] = w.w;
    }
    __syncthreads();
#pragma unroll 4
    for (int k = 0; k < 32; ++k) {
      float a0 = As[ty * 4 + 0][k], a1 = As[ty * 4 + 1][k];
      float a2 = As[ty * 4 + 2][k], a3 = As[ty * 4 + 3][k];
      float4 bA = *(const float4*)&Bs[k][tx * 8];
      float4 bB = *(const float4*)&Bs[k][tx * 8 + 4];
      float bv[8] = {bA.x, bA.y, bA.z, bA.w, bB.x, bB.y, bB.z, bB.w};
#pragma unroll
      for (int j = 0; j < 8; ++j) {
        acc[0][j] += a0 * bv[j];
        acc[1][j] += a1 * bv[j];
        acc[2][j] += a2 * bv[j];
        acc[3][j] += a3 * bv[j];
      }
    }
    __syncthreads();
  }

  int v = v0 + tx * 8;
  if (v < Vn) {
#pragma unroll
    for (int mi = 0; mi < 4; ++mi) {
      int b = b0 + ty * 4 + mi;
      float4 o0 = make_float4(acc[mi][0], acc[mi][1], acc[mi][2], acc[mi][3]);
      float4 o1 = make_float4(acc[mi][4], acc[mi][5], acc[mi][6], acc[mi][7]);
      *(float4*)(out + (size_t)b * Vn + v) = o0;
      *(float4*)(out + (size_t)b * Vn + v + 4) = o1;
    }
  }
}

// ---------------------------------------------------------------------------
// K5: tok[b] = argmax_v out[b,v]   (first-max tie-break like np.argmax)
// grid: (B), block 256
__global__ __launch_bounds__(256) void k_argmax(const float* __restrict__ out,
                                                int* __restrict__ tok) {
  __shared__ float vs[256];
  __shared__ int   is_[256];
  int b = blockIdx.x, tid = threadIdx.x;
  const float* p = out + (size_t)b * Vn;
  float bv = -3.402823466e38f;
  int bi = 0;
  for (int v = tid; v < Vn; v += 256) {
    float x = p[v];
    if (x > bv) { bv = x; bi = v; }
  }
  vs[tid] = bv; is_[tid] = bi;
  __syncthreads();
  for (int s = 128; s > 0; s >>= 1) {
    if (tid < s) {
      float v2 = vs[tid + s]; int i2 = is_[tid + s];
      if (v2 > vs[tid] || (v2 == vs[tid] && i2 < is_[tid])) { vs[tid] = v2; is_[tid] = i2; }
    }
    __syncthreads();
  }
  if (tid == 0) tok[b] = is_[0];
}

// ---------------------------------------------------------------------------
extern "C" void kernel_launch(void* const* d_in, const int* in_sizes, int n_in,
                              void* d_out, int out_size, void* d_ws, size_t ws_size,
                              hipStream_t stream) {
  const float* enc      = (const float*)d_in[0];
  const int*   lens     = (const int*)d_in[1];
  const float* emb      = (const float*)d_in[2];
  const float* w_ih     = (const float*)d_in[3];
  const float* w_hh     = (const float*)d_in[4];
  const float* b_ih     = (const float*)d_in[5];
  const float* b_hh     = (const float*)d_in[6];
  const float* attn_w   = (const float*)d_in[7];
  const float* concat_w = (const float*)d_in[8];
  const float* gamma    = (const float*)d_in[9];
  const float* beta     = (const float*)d_in[10];
  const float* proj_w   = (const float*)d_in[11];
  float* out = (float*)d_out;

  float* ws   = (float*)d_ws;
  float* h0   = ws;
  float* h1   = h0 + Bn * Hn;
  float* c0   = h1 + Bn * Hn;
  float* c1   = c0 + Bn * Hn;
  float* ctxv = c1 + Bn * Hn;
  float* tcat = ctxv + Bn * Hn;
  int*   tok  = (int*)(tcat + Bn * Hn);

  k_init<<<Bn, Hn, 0, stream>>>(enc, lens, h0, c0, tok);

  for (int t = 0; t < Tn; ++t) {
    const float* hi = (t & 1) ? h1 : h0;
    float*       ho = (t & 1) ? h0 : h1;
    const float* ci = (t & 1) ? c1 : c0;
    float*       co = (t & 1) ? c0 : c1;

    k_gates_lstm<<<dim3(Hn / 16, Bn / 64), 256, 0, stream>>>(
        emb, tok, w_ih, w_hh, b_ih, b_hh, hi, ci, ho, co);
    k_attn<<<Bn, 256, 0, stream>>>(enc, lens, attn_w, ho, ctxv);
    k_concat_ln<<<Bn, 256, 0, stream>>>(ho, ctxv, concat_w, gamma, beta, tcat);

    float* ot = out + (size_t)t * Bn * Vn;
    k_proj<<<dim3((Vn + 127) / 128, Bn / 64), 256, 0, stream>>>(tcat, proj_w, ot);
    k_argmax<<<Bn, 256, 0, stream>>>(ot, tok);
  }
}

// Round 2
// 2109.137 us; speedup vs baseline: 1.1146x; 1.1146x over previous
//
#include <hip/hip_runtime.h>

// Problem constants (PathDecoder): B=256, L=192, H=320, E=128, V=27000, T=8
constexpr int Bn = 256;
constexpr int Ln = 192;
constexpr int Hn = 320;
constexpr int En = 128;
constexpr int Vn = 27000;
constexpr int Tn = 8;
constexpr float NEGV   = -1e9f;
constexpr float LN_EPS = 1e-5f;

typedef __attribute__((ext_vector_type(8))) short bf16x8;
typedef __attribute__((ext_vector_type(4))) float f32x4;

__device__ __forceinline__ float sigmoidf_(float x) { return 1.f / (1.f + expf(-x)); }

__device__ __forceinline__ unsigned short f2bf(float x) {
  unsigned u = __float_as_uint(x);
  unsigned r = (u + 0x7fffu + ((u >> 16) & 1u)) >> 16;
  return (unsigned short)r;
}
__device__ __forceinline__ float bf2f(unsigned short h) {
  return __uint_as_float((unsigned)h << 16);
}

// ---------------------------------------------------------------------------
// K0: h0 = c0 = mean of context over valid length (pads are zero); tok = SOS=1
__global__ __launch_bounds__(320) void k_init(const float* __restrict__ ctx,
                                              const int* __restrict__ lens,
                                              float* __restrict__ h,
                                              float* __restrict__ c,
                                              int* __restrict__ tok) {
  int b = blockIdx.x, t = threadIdx.x;
  const float* p = ctx + (size_t)b * Ln * Hn + t;
  float s = 0.f;
  for (int l = 0; l < Ln; ++l) s += p[(size_t)l * Hn];
  float hv = s / (float)lens[b];
  h[b * Hn + t] = hv;
  c[b * Hn + t] = hv;
  if (t == 0) tok[b] = 1;
}

// ---------------------------------------------------------------------------
// Kprep: split proj_w (fp32 [V][K]) into bf16 hi/lo arrays (row-major [V][K])
__global__ __launch_bounds__(256) void k_split_w(const float* __restrict__ w,
                                                 unsigned short* __restrict__ hi,
                                                 unsigned short* __restrict__ lo,
                                                 int n4) {
  for (int i = blockIdx.x * 256 + threadIdx.x; i < n4; i += gridDim.x * 256) {
    float4 v = *(const float4*)(w + (size_t)i * 4);
    unsigned short h0 = f2bf(v.x), h1 = f2bf(v.y), h2 = f2bf(v.z), h3 = f2bf(v.w);
    unsigned short l0 = f2bf(v.x - bf2f(h0));
    unsigned short l1 = f2bf(v.y - bf2f(h1));
    unsigned short l2 = f2bf(v.z - bf2f(h2));
    unsigned short l3 = f2bf(v.w - bf2f(h3));
    ushort4 hv = make_ushort4(h0, h1, h2, h3);
    ushort4 lv = make_ushort4(l0, l1, l2, l3);
    *(ushort4*)(hi + (size_t)i * 4) = hv;
    *(ushort4*)(lo + (size_t)i * 4) = lv;
  }
}

// ---------------------------------------------------------------------------
// K1: gates = emb[tok] @ w_ih^T + h @ w_hh^T + b_ih + b_hh, then LSTM cell.
__global__ __launch_bounds__(256) void k_gates_lstm(
    const float* __restrict__ emb, const int* __restrict__ tok,
    const float* __restrict__ w_ih, const float* __restrict__ w_hh,
    const float* __restrict__ b_ih, const float* __restrict__ b_hh,
    const float* __restrict__ h_in, const float* __restrict__ c_in,
    float* __restrict__ h_out, float* __restrict__ c_out) {
  __shared__ float Xs[64][36];
  __shared__ float Ws[32][68];
  __shared__ float bias[64];
  __shared__ int   toks[64];

  int tid = threadIdx.x;
  int tx = tid & 15, ty = tid >> 4;
  int j0 = blockIdx.x * 16;
  int b0 = blockIdx.y * 64;

  if (tid < 64) {
    toks[tid] = tok[b0 + tid];
    int g = tid >> 4;
    int r = g * Hn + j0 + (tid & 15);
    bias[tid] = b_ih[r] + b_hh[r];
  }
  __syncthreads();

  float acc[4][4];
#pragma unroll
  for (int i = 0; i < 4; ++i)
#pragma unroll
    for (int j = 0; j < 4; ++j) acc[i][j] = 0.f;

  for (int k0 = 0; k0 < En + Hn; k0 += 32) {
#pragma unroll
    for (int jj = 0; jj < 2; ++jj) {
      int s = tid + jj * 256;
      int bl = s >> 3, k4 = s & 7;
      int k = k0 + k4 * 4;
      float4 v;
      if (k < En)
        v = *(const float4*)(emb + (size_t)toks[bl] * En + k);
      else
        v = *(const float4*)(h_in + (size_t)(b0 + bl) * Hn + (k - En));
      *(float4*)&Xs[bl][k4 * 4] = v;
    }
#pragma unroll
    for (int jj = 0; jj < 2; ++jj) {
      int s = tid + jj * 256;
      int rw = s >> 3, k4 = s & 7;
      int k = k0 + k4 * 4;
      int g = rw >> 4;
      int r = g * Hn + j0 + (rw & 15);
      float4 v;
      if (k < En)
        v = *(const float4*)(w_ih + (size_t)r * En + k);
      else
        v = *(const float4*)(w_hh + (size_t)r * Hn + (k - En));
      Ws[k4 * 4 + 0][rw] = v.x;
      Ws[k4 * 4 + 1][rw] = v.y;
      Ws[k4 * 4 + 2][rw] = v.z;
      Ws[k4 * 4 + 3][rw] = v.w;
    }
    __syncthreads();
#pragma unroll 4
    for (int k = 0; k < 32; ++k) {
      float a0 = Xs[ty * 4 + 0][k], a1 = Xs[ty * 4 + 1][k];
      float a2 = Xs[ty * 4 + 2][k], a3 = Xs[ty * 4 + 3][k];
      float w0 = Ws[k][tx], w1 = Ws[k][tx + 16], w2 = Ws[k][tx + 32], w3 = Ws[k][tx + 48];
      acc[0][0] += a0 * w0; acc[0][1] += a0 * w1; acc[0][2] += a0 * w2; acc[0][3] += a0 * w3;
      acc[1][0] += a1 * w0; acc[1][1] += a1 * w1; acc[1][2] += a1 * w2; acc[1][3] += a1 * w3;
      acc[2][0] += a2 * w0; acc[2][1] += a2 * w1; acc[2][2] += a2 * w2; acc[2][3] += a2 * w3;
      acc[3][0] += a3 * w0; acc[3][1] += a3 * w1; acc[3][2] += a3 * w2; acc[3][3] += a3 * w3;
    }
    __syncthreads();
  }

#pragma unroll
  for (int mi = 0; mi < 4; ++mi) {
    int b = b0 + ty * 4 + mi;
    int hc = j0 + tx;
    float iv = acc[mi][0] + bias[tx];
    float fv = acc[mi][1] + bias[16 + tx];
    float gv = acc[mi][2] + bias[32 + tx];
    float ov = acc[mi][3] + bias[48 + tx];
    float co = c_in[(size_t)b * Hn + hc];
    float cn = sigmoidf_(fv) * co + sigmoidf_(iv) * tanhf(gv);
    float hn = sigmoidf_(ov) * tanhf(cn);
    c_out[(size_t)b * Hn + hc] = cn;
    h_out[(size_t)b * Hn + hc] = hn;
  }
}

// ---------------------------------------------------------------------------
// K2: attention for one b per block
__global__ __launch_bounds__(256) void k_attn(
    const float* __restrict__ enc, const int* __restrict__ lens,
    const float* __restrict__ attn_w, const float* __restrict__ h_new,
    float* __restrict__ ctx_out) {
  __shared__ float hs[Hn];
  __shared__ float ahs[Hn];
  __shared__ float ss[Ln];
  __shared__ float red0, red1;

  int b = blockIdx.x, tid = threadIdx.x;
  for (int i = tid; i < Hn; i += 256) hs[i] = h_new[(size_t)b * Hn + i];
  __syncthreads();

  for (int i = tid; i < Hn; i += 256) {
    const float* w = attn_w + (size_t)i * Hn;
    float s = 0.f;
#pragma unroll 4
    for (int k = 0; k < Hn; ++k) s += w[k] * hs[k];
    ahs[i] = s;
  }
  __syncthreads();

  int lane = tid & 63, wv = tid >> 6;
  int len = lens[b];
  for (int l = wv; l < Ln; l += 4) {
    const float* cp = enc + ((size_t)b * Ln + l) * Hn;
    float s = 0.f;
#pragma unroll
    for (int c5 = 0; c5 < 5; ++c5) s += cp[lane + 64 * c5] * ahs[lane + 64 * c5];
#pragma unroll
    for (int off = 32; off > 0; off >>= 1) s += __shfl_xor(s, off, 64);
    if (lane == 0) ss[l] = s + ((l < len) ? 0.f : NEGV);
  }
  __syncthreads();

  if (tid < 64) {
    float m = -3.402823466e38f;
    for (int l = tid; l < Ln; l += 64) m = fmaxf(m, ss[l]);
#pragma unroll
    for (int off = 32; off > 0; off >>= 1) m = fmaxf(m, __shfl_xor(m, off, 64));
    if (tid == 0) red0 = m;
  }
  __syncthreads();
  float m = red0;
  for (int l = tid; l < Ln; l += 256) ss[l] = expf(ss[l] - m);
  __syncthreads();
  if (tid < 64) {
    float s = 0.f;
    for (int l = tid; l < Ln; l += 64) s += ss[l];
#pragma unroll
    for (int off = 32; off > 0; off >>= 1) s += __shfl_xor(s, off, 64);
    if (tid == 0) red1 = s;
  }
  __syncthreads();
  float inv = 1.f / red1;
  for (int l = tid; l < Ln; l += 256) ss[l] *= inv;
  __syncthreads();

  for (int h = tid; h < Hn; h += 256) {
    const float* cp = enc + (size_t)b * Ln * Hn + h;
    float a = 0.f;
#pragma unroll 4
    for (int l = 0; l < Ln; ++l) a += ss[l] * cp[(size_t)l * Hn];
    ctx_out[(size_t)b * Hn + h] = a;
  }
}

// ---------------------------------------------------------------------------
// K3: cat = [h,ctx] @ concat_w^T ; LayerNorm ; tanh -> tcat (bf16 hi/lo)
__global__ __launch_bounds__(256) void k_concat_ln(
    const float* __restrict__ h_new, const float* __restrict__ ctxv,
    const float* __restrict__ cw, const float* __restrict__ gamma,
    const float* __restrict__ beta,
    unsigned short* __restrict__ t_hi, unsigned short* __restrict__ t_lo) {
  __shared__ float xs[2 * Hn];
  __shared__ float cs[Hn];
  __shared__ float mu_s, var_s;

  int b = blockIdx.x, tid = threadIdx.x;
  for (int i = tid; i < Hn; i += 256) {
    xs[i] = h_new[(size_t)b * Hn + i];
    xs[Hn + i] = ctxv[(size_t)b * Hn + i];
  }
  __syncthreads();

  for (int i = tid; i < Hn; i += 256) {
    const float* w = cw + (size_t)i * (2 * Hn);
    float s = 0.f;
#pragma unroll 4
    for (int k = 0; k < 2 * Hn; ++k) s += w[k] * xs[k];
    cs[i] = s;
  }
  __syncthreads();

  if (tid < 64) {
    float s = 0.f;
    for (int i = tid; i < Hn; i += 64) s += cs[i];
#pragma unroll
    for (int off = 32; off > 0; off >>= 1) s += __shfl_xor(s, off, 64);
    if (tid == 0) mu_s = s / (float)Hn;
  }
  __syncthreads();
  float mu = mu_s;
  if (tid < 64) {
    float s = 0.f;
    for (int i = tid; i < Hn; i += 64) { float d = cs[i] - mu; s += d * d; }
#pragma unroll
    for (int off = 32; off > 0; off >>= 1) s += __shfl_xor(s, off, 64);
    if (tid == 0) var_s = s / (float)Hn;
  }
  __syncthreads();
  float rstd = 1.f / sqrtf(var_s + LN_EPS);
  for (int i = tid; i < Hn; i += 256) {
    float y = (cs[i] - mu) * rstd * gamma[i] + beta[i];
    float t = tanhf(y);
    unsigned short th = f2bf(t);
    unsigned short tl = f2bf(t - bf2f(th));
    t_hi[(size_t)b * Hn + i] = th;
    t_lo[(size_t)b * Hn + i] = tl;
  }
}

// ---------------------------------------------------------------------------
// K4: out[b,v] = tcat[b,:] . proj_w[v,:]  via split-bf16 MFMA.
// D = Ahi*Bhi + Ahi*Blo + Alo*Bhi  (fp32 accumulate)
// grid: (ceil(V/256)=106, B/64=4), block 256 (4 waves), wave tile 64b x 64v.
__global__ __launch_bounds__(256) void k_proj_mfma(
    const unsigned short* __restrict__ a_hi, const unsigned short* __restrict__ a_lo,
    const unsigned short* __restrict__ b_hi, const unsigned short* __restrict__ b_lo,
    float* __restrict__ out) {
  int tid = threadIdx.x;
  int wave = tid >> 6, lane = tid & 63;
  int v0 = blockIdx.x * 256 + wave * 64;
  int b0 = blockIdx.y * 64;

  int lr = lane & 15;
  int kg = (lane >> 4) * 8;

  f32x4 acc[4][4];
#pragma unroll
  for (int i = 0; i < 4; ++i)
#pragma unroll
    for (int j = 0; j < 4; ++j) acc[i][j] = (f32x4){0.f, 0.f, 0.f, 0.f};

  const bf16x8 zf = {0, 0, 0, 0, 0, 0, 0, 0};

  for (int k0 = 0; k0 < Hn; k0 += 32) {
    bf16x8 af[4][2], bfv[4][2];
#pragma unroll
    for (int mt = 0; mt < 4; ++mt) {
      size_t ra = (size_t)(b0 + mt * 16 + lr) * Hn + k0 + kg;
      af[mt][0] = *(const bf16x8*)(a_hi + ra);
      af[mt][1] = *(const bf16x8*)(a_lo + ra);
    }
#pragma unroll
    for (int nt = 0; nt < 4; ++nt) {
      int v = v0 + nt * 16 + lr;
      if (v < Vn) {
        size_t rb = (size_t)v * Hn + k0 + kg;
        bfv[nt][0] = *(const bf16x8*)(b_hi + rb);
        bfv[nt][1] = *(const bf16x8*)(b_lo + rb);
      } else {
        bfv[nt][0] = zf;
        bfv[nt][1] = zf;
      }
    }
#pragma unroll
    for (int mt = 0; mt < 4; ++mt)
#pragma unroll
      for (int nt = 0; nt < 4; ++nt) {
        acc[mt][nt] = __builtin_amdgcn_mfma_f32_16x16x32_bf16(af[mt][0], bfv[nt][0], acc[mt][nt], 0, 0, 0);
        acc[mt][nt] = __builtin_amdgcn_mfma_f32_16x16x32_bf16(af[mt][0], bfv[nt][1], acc[mt][nt], 0, 0, 0);
        acc[mt][nt] = __builtin_amdgcn_mfma_f32_16x16x32_bf16(af[mt][1], bfv[nt][0], acc[mt][nt], 0, 0, 0);
      }
  }

  int orow = (lane >> 4) * 4;
#pragma unroll
  for (int mt = 0; mt < 4; ++mt)
#pragma unroll
    for (int nt = 0; nt < 4; ++nt) {
      int v = v0 + nt * 16 + lr;
      if (v < Vn) {
#pragma unroll
        for (int j = 0; j < 4; ++j)
          out[(size_t)(b0 + mt * 16 + orow + j) * Vn + v] = acc[mt][nt][j];
      }
    }
}

// ---------------------------------------------------------------------------
// K5: tok[b] = argmax_v out[b,v]
__global__ __launch_bounds__(256) void k_argmax(const float* __restrict__ out,
                                                int* __restrict__ tok) {
  __shared__ float vs[256];
  __shared__ int   is_[256];
  int b = blockIdx.x, tid = threadIdx.x;
  const float* p = out + (size_t)b * Vn;
  float bv = -3.402823466e38f;
  int bi = 0;
  for (int v = tid; v < Vn; v += 256) {
    float x = p[v];
    if (x > bv) { bv = x; bi = v; }
  }
  vs[tid] = bv; is_[tid] = bi;
  __syncthreads();
  for (int s = 128; s > 0; s >>= 1) {
    if (tid < s) {
      float v2 = vs[tid + s]; int i2 = is_[tid + s];
      if (v2 > vs[tid] || (v2 == vs[tid] && i2 < is_[tid])) { vs[tid] = v2; is_[tid] = i2; }
    }
    __syncthreads();
  }
  if (tid == 0) tok[b] = is_[0];
}

// ---------------------------------------------------------------------------
extern "C" void kernel_launch(void* const* d_in, const int* in_sizes, int n_in,
                              void* d_out, int out_size, void* d_ws, size_t ws_size,
                              hipStream_t stream) {
  const float* enc      = (const float*)d_in[0];
  const int*   lens     = (const int*)d_in[1];
  const float* emb      = (const float*)d_in[2];
  const float* w_ih     = (const float*)d_in[3];
  const float* w_hh     = (const float*)d_in[4];
  const float* b_ih     = (const float*)d_in[5];
  const float* b_hh     = (const float*)d_in[6];
  const float* attn_w   = (const float*)d_in[7];
  const float* concat_w = (const float*)d_in[8];
  const float* gamma    = (const float*)d_in[9];
  const float* beta     = (const float*)d_in[10];
  const float* proj_w   = (const float*)d_in[11];
  float* out = (float*)d_out;

  // workspace layout (floats unless noted)
  float* ws   = (float*)d_ws;
  float* h0   = ws;
  float* h1   = h0 + Bn * Hn;
  float* c0   = h1 + Bn * Hn;
  float* c1   = c0 + Bn * Hn;
  float* ctxv = c1 + Bn * Hn;
  int*   tok  = (int*)(ctxv + Bn * Hn);
  unsigned short* t_hi = (unsigned short*)(tok + Bn);
  unsigned short* t_lo = t_hi + Bn * Hn;
  unsigned short* pw_hi = t_lo + Bn * Hn;            // [V][K] bf16
  unsigned short* pw_lo = pw_hi + (size_t)Vn * Hn;   // [V][K] bf16

  k_split_w<<<2048, 256, 0, stream>>>(proj_w, pw_hi, pw_lo, Vn * Hn / 4);
  k_init<<<Bn, Hn, 0, stream>>>(enc, lens, h0, c0, tok);

  for (int t = 0; t < Tn; ++t) {
    const float* hi = (t & 1) ? h1 : h0;
    float*       ho = (t & 1) ? h0 : h1;
    const float* ci = (t & 1) ? c1 : c0;
    float*       co = (t & 1) ? c0 : c1;

    k_gates_lstm<<<dim3(Hn / 16, Bn / 64), 256, 0, stream>>>(
        emb, tok, w_ih, w_hh, b_ih, b_hh, hi, ci, ho, co);
    k_attn<<<Bn, 256, 0, stream>>>(enc, lens, attn_w, ho, ctxv);
    k_concat_ln<<<Bn, 256, 0, stream>>>(ho, ctxv, concat_w, gamma, beta, t_hi, t_lo);

    float* ot = out + (size_t)t * Bn * Vn;
    k_proj_mfma<<<dim3((Vn + 255) / 256, Bn / 64), 256, 0, stream>>>(t_hi, t_lo, pw_hi, pw_lo, ot);
    k_argmax<<<Bn, 256, 0, stream>>>(ot, tok);
  }
}

// Round 3
// 1902.027 us; speedup vs baseline: 1.2360x; 1.1089x over previous
//
#include <hip/hip_runtime.h>

// PathDecoder: B=256, L=192, H=320, E=128, V=27000, T=8
constexpr int Bn = 256;
constexpr int Ln = 192;
constexpr int Hn = 320;
constexpr int En = 128;
constexpr int Vn = 27000;
constexpr int Tn = 8;
constexpr float NEGV   = -1e9f;
constexpr float LN_EPS = 1e-5f;

typedef __attribute__((ext_vector_type(8))) short bf16x8;
typedef __attribute__((ext_vector_type(4))) float f32x4;
typedef unsigned long long u64;

__device__ __forceinline__ float sigmoidf_(float x) { return 1.f / (1.f + expf(-x)); }

__device__ __forceinline__ unsigned short f2bf(float x) {
  unsigned u = __float_as_uint(x);
  return (unsigned short)((u + 0x7fffu + ((u >> 16) & 1u)) >> 16);
}
__device__ __forceinline__ float bf2f(unsigned short h) {
  return __uint_as_float((unsigned)h << 16);
}
// monotone float->u32 (order-preserving over all finite values)
__device__ __forceinline__ unsigned mono(float f) {
  unsigned u = __float_as_uint(f);
  return (u & 0x80000000u) ? ~u : (u | 0x80000000u);
}
__device__ __forceinline__ u64 shfl_xor_u64(u64 x, int off) {
  unsigned lo = (unsigned)x, hi = (unsigned)(x >> 32);
  lo = __shfl_xor(lo, off, 64);
  hi = __shfl_xor(hi, off, 64);
  return ((u64)hi << 32) | lo;
}

// ---------------------------------------------------------------------------
// split fp32 -> bf16 hi/lo
__global__ __launch_bounds__(256) void k_split(const float* __restrict__ w,
                                               unsigned short* __restrict__ hi,
                                               unsigned short* __restrict__ lo,
                                               int n4) {
  for (int i = blockIdx.x * 256 + threadIdx.x; i < n4; i += gridDim.x * 256) {
    float4 v = *(const float4*)(w + (size_t)i * 4);
    unsigned short h0 = f2bf(v.x), h1 = f2bf(v.y), h2 = f2bf(v.z), h3 = f2bf(v.w);
    ushort4 hv = make_ushort4(h0, h1, h2, h3);
    ushort4 lv = make_ushort4(f2bf(v.x - bf2f(h0)), f2bf(v.y - bf2f(h1)),
                              f2bf(v.z - bf2f(h2)), f2bf(v.w - bf2f(h3)));
    *(ushort4*)(hi + (size_t)i * 4) = hv;
    *(ushort4*)(lo + (size_t)i * 4) = lv;
  }
}

// ---------------------------------------------------------------------------
// h0 = c0 = mean over valid length; zero the argmax slots
__global__ __launch_bounds__(320) void k_init(const float* __restrict__ ctx,
                                              const int* __restrict__ lens,
                                              float* __restrict__ h,
                                              float* __restrict__ c,
                                              u64* __restrict__ amax) {
  int b = blockIdx.x, t = threadIdx.x;
  const float* p = ctx + (size_t)b * Ln * Hn + t;
  float s = 0.f;
  for (int l = 0; l < Ln; ++l) s += p[(size_t)l * Hn];
  float hv = s / (float)lens[b];
  h[b * Hn + t] = hv;
  c[b * Hn + t] = hv;
  if (b < Tn && t < Bn) amax[b * Bn + t] = 0ull;
}

// ---------------------------------------------------------------------------
// gates + LSTM cell; token from previous step's fused argmax slots.
// Also writes h as split-bf16 into xc[:, 0:320].
__global__ __launch_bounds__(256) void k_gates_lstm(
    const float* __restrict__ emb, const u64* __restrict__ amax, int step,
    const float* __restrict__ w_ih, const float* __restrict__ w_hh,
    const float* __restrict__ b_ih, const float* __restrict__ b_hh,
    const float* __restrict__ h_in, const float* __restrict__ c_in,
    float* __restrict__ h_out, float* __restrict__ c_out,
    unsigned short* __restrict__ xc_hi, unsigned short* __restrict__ xc_lo) {
  __shared__ float Xs[64][36];
  __shared__ float Ws[32][68];
  __shared__ float bias[64];
  __shared__ int   toks[64];

  int tid = threadIdx.x;
  int tx = tid & 15, ty = tid >> 4;
  int j0 = blockIdx.x * 16;
  int b0 = blockIdx.y * 64;

  if (tid < 64) {
    int tk;
    if (step == 0) tk = 1;
    else tk = (int)(~(unsigned)amax[(size_t)(step - 1) * Bn + b0 + tid]);
    toks[tid] = tk;
    int g = tid >> 4;
    int r = g * Hn + j0 + (tid & 15);
    bias[tid] = b_ih[r] + b_hh[r];
  }
  __syncthreads();

  float acc[4][4];
#pragma unroll
  for (int i = 0; i < 4; ++i)
#pragma unroll
    for (int j = 0; j < 4; ++j) acc[i][j] = 0.f;

  for (int k0 = 0; k0 < En + Hn; k0 += 32) {
#pragma unroll
    for (int jj = 0; jj < 2; ++jj) {
      int s = tid + jj * 256;
      int bl = s >> 3, k4 = s & 7;
      int k = k0 + k4 * 4;
      float4 v;
      if (k < En)
        v = *(const float4*)(emb + (size_t)toks[bl] * En + k);
      else
        v = *(const float4*)(h_in + (size_t)(b0 + bl) * Hn + (k - En));
      *(float4*)&Xs[bl][k4 * 4] = v;
    }
#pragma unroll
    for (int jj = 0; jj < 2; ++jj) {
      int s = tid + jj * 256;
      int rw = s >> 3, k4 = s & 7;
      int k = k0 + k4 * 4;
      int g = rw >> 4;
      int r = g * Hn + j0 + (rw & 15);
      float4 v;
      if (k < En)
        v = *(const float4*)(w_ih + (size_t)r * En + k);
      else
        v = *(const float4*)(w_hh + (size_t)r * Hn + (k - En));
      Ws[k4 * 4 + 0][rw] = v.x;
      Ws[k4 * 4 + 1][rw] = v.y;
      Ws[k4 * 4 + 2][rw] = v.z;
      Ws[k4 * 4 + 3][rw] = v.w;
    }
    __syncthreads();
#pragma unroll 4
    for (int k = 0; k < 32; ++k) {
      float a0 = Xs[ty * 4 + 0][k], a1 = Xs[ty * 4 + 1][k];
      float a2 = Xs[ty * 4 + 2][k], a3 = Xs[ty * 4 + 3][k];
      float w0 = Ws[k][tx], w1 = Ws[k][tx + 16], w2 = Ws[k][tx + 32], w3 = Ws[k][tx + 48];
      acc[0][0] += a0 * w0; acc[0][1] += a0 * w1; acc[0][2] += a0 * w2; acc[0][3] += a0 * w3;
      acc[1][0] += a1 * w0; acc[1][1] += a1 * w1; acc[1][2] += a1 * w2; acc[1][3] += a1 * w3;
      acc[2][0] += a2 * w0; acc[2][1] += a2 * w1; acc[2][2] += a2 * w2; acc[2][3] += a2 * w3;
      acc[3][0] += a3 * w0; acc[3][1] += a3 * w1; acc[3][2] += a3 * w2; acc[3][3] += a3 * w3;
    }
    __syncthreads();
  }

#pragma unroll
  for (int mi = 0; mi < 4; ++mi) {
    int b = b0 + ty * 4 + mi;
    int hc = j0 + tx;
    float iv = acc[mi][0] + bias[tx];
    float fv = acc[mi][1] + bias[16 + tx];
    float gv = acc[mi][2] + bias[32 + tx];
    float ov = acc[mi][3] + bias[48 + tx];
    float co = c_in[(size_t)b * Hn + hc];
    float cn = sigmoidf_(fv) * co + sigmoidf_(iv) * tanhf(gv);
    float hn = sigmoidf_(ov) * tanhf(cn);
    c_out[(size_t)b * Hn + hc] = cn;
    h_out[(size_t)b * Hn + hc] = hn;
    unsigned short th = f2bf(hn);
    xc_hi[(size_t)b * (2 * Hn) + hc] = th;
    xc_lo[(size_t)b * (2 * Hn) + hc] = f2bf(hn - bf2f(th));
  }
}

// ---------------------------------------------------------------------------
// attention (ah + scores + softmax + ctx) for one b; block = 512 (8 waves).
// ctx written as split-bf16 into xc[:, 320:640].
__global__ __launch_bounds__(512) void k_attn(
    const float* __restrict__ enc, const int* __restrict__ lens,
    const float* __restrict__ attn_w, const float* __restrict__ h_new,
    unsigned short* __restrict__ xc_hi, unsigned short* __restrict__ xc_lo) {
  __shared__ float hs[Hn];
  __shared__ float ahs[Hn];
  __shared__ float ss[Ln];
  __shared__ float red0, red1;

  int b = blockIdx.x, tid = threadIdx.x;
  if (tid < Hn) hs[tid] = h_new[(size_t)b * Hn + tid];
  __syncthreads();

  // ah[i] = attn_w[i,:] . h
  if (tid < Hn) {
    const float4* w = (const float4*)(attn_w + (size_t)tid * Hn);
    float s = 0.f;
#pragma unroll 4
    for (int k4 = 0; k4 < Hn / 4; ++k4) {
      float4 v = w[k4];
      s += v.x * hs[k4 * 4] + v.y * hs[k4 * 4 + 1] + v.z * hs[k4 * 4 + 2] + v.w * hs[k4 * 4 + 3];
    }
    ahs[tid] = s;
  }
  __syncthreads();

  // scores: wave-per-row, coalesced
  int lane = tid & 63, wv = tid >> 6;
  int len = lens[b];
  for (int l = wv; l < Ln; l += 8) {
    const float* cp = enc + ((size_t)b * Ln + l) * Hn;
    float s = 0.f;
#pragma unroll
    for (int c5 = 0; c5 < 5; ++c5) s += cp[lane + 64 * c5] * ahs[lane + 64 * c5];
#pragma unroll
    for (int off = 32; off > 0; off >>= 1) s += __shfl_xor(s, off, 64);
    if (lane == 0) ss[l] = s + ((l < len) ? 0.f : NEGV);
  }
  __syncthreads();

  // softmax over L=192
  if (tid < 64) {
    float m = -3.402823466e38f;
    for (int l = tid; l < Ln; l += 64) m = fmaxf(m, ss[l]);
#pragma unroll
    for (int off = 32; off > 0; off >>= 1) m = fmaxf(m, __shfl_xor(m, off, 64));
    if (tid == 0) red0 = m;
  }
  __syncthreads();
  float m = red0;
  if (tid < Ln) ss[tid] = expf(ss[tid] - m);
  __syncthreads();
  if (tid < 64) {
    float s = 0.f;
    for (int l = tid; l < Ln; l += 64) s += ss[l];
#pragma unroll
    for (int off = 32; off > 0; off >>= 1) s += __shfl_xor(s, off, 64);
    if (tid == 0) red1 = s;
  }
  __syncthreads();
  float inv = 1.f / red1;
  if (tid < Ln) ss[tid] *= inv;
  __syncthreads();

  // ctx[h] = sum_l p[l] * enc[b,l,h]
  if (tid < Hn) {
    const float* cp = enc + (size_t)b * Ln * Hn + tid;
    float a = 0.f;
#pragma unroll 8
    for (int l = 0; l < Ln; ++l) a += ss[l] * cp[(size_t)l * Hn];
    unsigned short th = f2bf(a);
    xc_hi[(size_t)b * (2 * Hn) + Hn + tid] = th;
    xc_lo[(size_t)b * (2 * Hn) + Hn + tid] = f2bf(a - bf2f(th));
  }
}

// ---------------------------------------------------------------------------
// cat = xc @ concat_w^T (split-bf16 MFMA), fused LayerNorm + tanh + split.
// grid: (B/64), block 512 = 8 waves (4 m x 2 n). Per block: 64 rows x 320 cols.
__global__ __launch_bounds__(512) void k_cat_ln(
    const unsigned short* __restrict__ xc_hi, const unsigned short* __restrict__ xc_lo,
    const unsigned short* __restrict__ cw_hi, const unsigned short* __restrict__ cw_lo,
    const float* __restrict__ gamma, const float* __restrict__ beta,
    unsigned short* __restrict__ t_hi, unsigned short* __restrict__ t_lo) {
  __shared__ float S1[2][4][16];
  __shared__ float S2[2][4][16];

  int tid = threadIdx.x;
  int wave = tid >> 6, lane = tid & 63;
  int wm = wave >> 1, wn = wave & 1;
  int b0 = blockIdx.x * 64;
  int lr = lane & 15, hi4 = lane >> 4;
  int kg = hi4 * 8;

  f32x4 acc[10];
#pragma unroll
  for (int i = 0; i < 10; ++i) acc[i] = (f32x4){0.f, 0.f, 0.f, 0.f};

  for (int k0 = 0; k0 < 2 * Hn; k0 += 32) {
    size_t ra = (size_t)(b0 + wm * 16 + lr) * (2 * Hn) + k0 + kg;
    bf16x8 ah_ = *(const bf16x8*)(xc_hi + ra);
    bf16x8 al_ = *(const bf16x8*)(xc_lo + ra);
#pragma unroll
    for (int nt = 0; nt < 10; ++nt) {
      int c = wn * 160 + nt * 16 + lr;
      size_t rb = (size_t)c * (2 * Hn) + k0 + kg;
      bf16x8 bh_ = *(const bf16x8*)(cw_hi + rb);
      bf16x8 bl_ = *(const bf16x8*)(cw_lo + rb);
      acc[nt] = __builtin_amdgcn_mfma_f32_16x16x32_bf16(ah_, bh_, acc[nt], 0, 0, 0);
      acc[nt] = __builtin_amdgcn_mfma_f32_16x16x32_bf16(ah_, bl_, acc[nt], 0, 0, 0);
      acc[nt] = __builtin_amdgcn_mfma_f32_16x16x32_bf16(al_, bh_, acc[nt], 0, 0, 0);
    }
  }

  // per-row mean/var across 320 cols: lane partial (10 cols) -> 16-lane shfl -> LDS
  float s1[4] = {0.f, 0.f, 0.f, 0.f}, s2[4] = {0.f, 0.f, 0.f, 0.f};
#pragma unroll
  for (int nt = 0; nt < 10; ++nt)
#pragma unroll
    for (int j = 0; j < 4; ++j) {
      float v = acc[nt][j];
      s1[j] += v;
      s2[j] += v * v;
    }
#pragma unroll
  for (int off = 1; off < 16; off <<= 1)
#pragma unroll
    for (int j = 0; j < 4; ++j) {
      s1[j] += __shfl_xor(s1[j], off, 64);
      s2[j] += __shfl_xor(s2[j], off, 64);
    }
  if (lr == 0) {
#pragma unroll
    for (int j = 0; j < 4; ++j) {
      S1[wn][wm][hi4 * 4 + j] = s1[j];
      S2[wn][wm][hi4 * 4 + j] = s2[j];
    }
  }
  __syncthreads();

#pragma unroll
  for (int j = 0; j < 4; ++j) {
    int r = hi4 * 4 + j;
    float tot1 = S1[0][wm][r] + S1[1][wm][r];
    float tot2 = S2[0][wm][r] + S2[1][wm][r];
    float mu = tot1 * (1.f / 320.f);
    float var = tot2 * (1.f / 320.f) - mu * mu;
    float rstd = 1.f / sqrtf(var + LN_EPS);
    int row = b0 + wm * 16 + r;
#pragma unroll
    for (int nt = 0; nt < 10; ++nt) {
      int c = wn * 160 + nt * 16 + lr;
      float y = (acc[nt][j] - mu) * rstd * gamma[c] + beta[c];
      float tv = tanhf(y);
      unsigned short th = f2bf(tv);
      t_hi[(size_t)row * Hn + c] = th;
      t_lo[(size_t)row * Hn + c] = f2bf(tv - bf2f(th));
    }
  }
}

// ---------------------------------------------------------------------------
// projection (split-bf16 MFMA) + fused argmax via packed u64 atomicMax.
__global__ __launch_bounds__(256) void k_proj(
    const unsigned short* __restrict__ a_hi, const unsigned short* __restrict__ a_lo,
    const unsigned short* __restrict__ b_hi, const unsigned short* __restrict__ b_lo,
    float* __restrict__ out, u64* __restrict__ amax, int step) {
  __shared__ u64 red[4][64];

  int tid = threadIdx.x;
  int wave = tid >> 6, lane = tid & 63;
  int v0 = blockIdx.x * 256 + wave * 64;
  int b0 = blockIdx.y * 64;
  int lr = lane & 15, hi4 = lane >> 4;
  int kg = hi4 * 8;

  f32x4 acc[4][4];
#pragma unroll
  for (int i = 0; i < 4; ++i)
#pragma unroll
    for (int j = 0; j < 4; ++j) acc[i][j] = (f32x4){0.f, 0.f, 0.f, 0.f};

  const bf16x8 zf = {0, 0, 0, 0, 0, 0, 0, 0};

  for (int k0 = 0; k0 < Hn; k0 += 32) {
    bf16x8 af[4][2], bfv[4][2];
#pragma unroll
    for (int mt = 0; mt < 4; ++mt) {
      size_t ra = (size_t)(b0 + mt * 16 + lr) * Hn + k0 + kg;
      af[mt][0] = *(const bf16x8*)(a_hi + ra);
      af[mt][1] = *(const bf16x8*)(a_lo + ra);
    }
#pragma unroll
    for (int nt = 0; nt < 4; ++nt) {
      int v = v0 + nt * 16 + lr;
      if (v < Vn) {
        size_t rb = (size_t)v * Hn + k0 + kg;
        bfv[nt][0] = *(const bf16x8*)(b_hi + rb);
        bfv[nt][1] = *(const bf16x8*)(b_lo + rb);
      } else {
        bfv[nt][0] = zf;
        bfv[nt][1] = zf;
      }
    }
#pragma unroll
    for (int mt = 0; mt < 4; ++mt)
#pragma unroll
      for (int nt = 0; nt < 4; ++nt) {
        acc[mt][nt] = __builtin_amdgcn_mfma_f32_16x16x32_bf16(af[mt][0], bfv[nt][0], acc[mt][nt], 0, 0, 0);
        acc[mt][nt] = __builtin_amdgcn_mfma_f32_16x16x32_bf16(af[mt][0], bfv[nt][1], acc[mt][nt], 0, 0, 0);
        acc[mt][nt] = __builtin_amdgcn_mfma_f32_16x16x32_bf16(af[mt][1], bfv[nt][0], acc[mt][nt], 0, 0, 0);
      }
  }

  int orow = hi4 * 4;
  // store logits
#pragma unroll
  for (int mt = 0; mt < 4; ++mt)
#pragma unroll
    for (int nt = 0; nt < 4; ++nt) {
      int v = v0 + nt * 16 + lr;
      if (v < Vn) {
#pragma unroll
        for (int j = 0; j < 4; ++j)
          out[(size_t)(b0 + mt * 16 + orow + j) * Vn + v] = acc[mt][nt][j];
      }
    }

  // fused argmax: key = (mono(value)<<32) | ~index ; max-key == first max value
  u64 best[4][4];
#pragma unroll
  for (int mt = 0; mt < 4; ++mt)
#pragma unroll
    for (int j = 0; j < 4; ++j) {
      u64 k = 0ull;
#pragma unroll
      for (int nt = 0; nt < 4; ++nt) {
        int v = v0 + nt * 16 + lr;
        if (v < Vn) {
          u64 kk = ((u64)mono(acc[mt][nt][j]) << 32) | (u64)(unsigned)(~v);
          if (kk > k) k = kk;
        }
      }
      best[mt][j] = k;
    }
#pragma unroll
  for (int off = 1; off < 16; off <<= 1)
#pragma unroll
    for (int mt = 0; mt < 4; ++mt)
#pragma unroll
      for (int j = 0; j < 4; ++j) {
        u64 o = shfl_xor_u64(best[mt][j], off);
        if (o > best[mt][j]) best[mt][j] = o;
      }
  if (lr == 0) {
#pragma unroll
    for (int mt = 0; mt < 4; ++mt)
#pragma unroll
      for (int j = 0; j < 4; ++j) red[wave][mt * 16 + orow + j] = best[mt][j];
  }
  __syncthreads();
  if (tid < 64) {
    u64 k = red[0][tid];
#pragma unroll
    for (int w = 1; w < 4; ++w)
      if (red[w][tid] > k) k = red[w][tid];
    atomicMax(&amax[(size_t)step * Bn + b0 + tid], k);
  }
}

// ---------------------------------------------------------------------------
extern "C" void kernel_launch(void* const* d_in, const int* in_sizes, int n_in,
                              void* d_out, int out_size, void* d_ws, size_t ws_size,
                              hipStream_t stream) {
  const float* enc      = (const float*)d_in[0];
  const int*   lens     = (const int*)d_in[1];
  const float* emb      = (const float*)d_in[2];
  const float* w_ih     = (const float*)d_in[3];
  const float* w_hh     = (const float*)d_in[4];
  const float* b_ih     = (const float*)d_in[5];
  const float* b_hh     = (const float*)d_in[6];
  const float* attn_w   = (const float*)d_in[7];
  const float* concat_w = (const float*)d_in[8];
  const float* gamma    = (const float*)d_in[9];
  const float* beta     = (const float*)d_in[10];
  const float* proj_w   = (const float*)d_in[11];
  float* out = (float*)d_out;

  float* ws = (float*)d_ws;
  float* h0 = ws;                       // 256*320
  float* h1 = h0 + Bn * Hn;
  float* c0 = h1 + Bn * Hn;
  float* c1 = c0 + Bn * Hn;
  u64* amax = (u64*)(c1 + Bn * Hn);     // 8*256 u64
  unsigned short* xc_hi = (unsigned short*)(amax + Tn * Bn);  // 256*640
  unsigned short* xc_lo = xc_hi + Bn * 2 * Hn;
  unsigned short* t_hi  = xc_lo + Bn * 2 * Hn;                // 256*320
  unsigned short* t_lo  = t_hi + Bn * Hn;
  unsigned short* cw_hi = t_lo + Bn * Hn;                     // 320*640
  unsigned short* cw_lo = cw_hi + Hn * 2 * Hn;
  unsigned short* pw_hi = cw_lo + Hn * 2 * Hn;                // 27000*320
  unsigned short* pw_lo = pw_hi + (size_t)Vn * Hn;

  k_split<<<2048, 256, 0, stream>>>(proj_w, pw_hi, pw_lo, Vn * Hn / 4);
  k_split<<<256, 256, 0, stream>>>(concat_w, cw_hi, cw_lo, Hn * 2 * Hn / 4);
  k_init<<<Bn, Hn, 0, stream>>>(enc, lens, h0, c0, amax);

  for (int t = 0; t < Tn; ++t) {
    const float* hi = (t & 1) ? h1 : h0;
    float*       ho = (t & 1) ? h0 : h1;
    const float* ci = (t & 1) ? c1 : c0;
    float*       co = (t & 1) ? c0 : c1;

    k_gates_lstm<<<dim3(Hn / 16, Bn / 64), 256, 0, stream>>>(
        emb, amax, t, w_ih, w_hh, b_ih, b_hh, hi, ci, ho, co, xc_hi, xc_lo);
    k_attn<<<Bn, 512, 0, stream>>>(enc, lens, attn_w, ho, xc_hi, xc_lo);
    k_cat_ln<<<Bn / 64, 512, 0, stream>>>(xc_hi, xc_lo, cw_hi, cw_lo, gamma, beta, t_hi, t_lo);

    float* ot = out + (size_t)t * Bn * Vn;
    k_proj<<<dim3((Vn + 255) / 256, Bn / 64), 256, 0, stream>>>(
        t_hi, t_lo, pw_hi, pw_lo, ot, amax, t);
  }
}